// Round 7
// baseline (122.383 us; speedup 1.0000x reference)
//
#include <hip/hip_runtime.h>
#include <hip/hip_fp16.h>

// Problem constants
constexpr int B_TOT = 8192;      // batch
constexpr int NM    = 64;        // n_models
constexpr int TT    = 16;        // trees per split
constexpr int LF    = 64;       // maxleaf
constexpr int EM    = 32;        // emb dim
constexpr int XROW  = NM * TT;   // 1024 ints per x row
constexpr int TROWS = TT * LF;   // 1024 rows per model table

// Broadcast quad-lane TQ's int4 to all 4 lanes of each quad via DPP
// (VALU pipe — does NOT load the LDS pipe like __shfl/ds_bpermute would).
template<int TQ>
__device__ __forceinline__ int4 qbcast(int4 v) {
    constexpr int c = TQ * 0x55;          // quad_perm [TQ,TQ,TQ,TQ]
    int4 r;
    r.x = __builtin_amdgcn_mov_dpp(v.x, c, 0xf, 0xf, true);
    r.y = __builtin_amdgcn_mov_dpp(v.y, c, 0xf, 0xf, true);
    r.z = __builtin_amdgcn_mov_dpp(v.z, c, 0xf, 0xf, true);
    r.w = __builtin_amdgcn_mov_dpp(v.w, c, 0xf, 0xf, true);
    return r;
}

__device__ __forceinline__ __half2 H2(unsigned u) { return *(const __half2*)&u; }

// ---------------------------------------------------------------------------
// K1': per-channel batch stats. Inner loop byte-identical to the proven R0
// kernel; R7 change is ONLY the blocking: 4 chunks x 1024-thr blocks
// (256 blocks) instead of 8 chunks x 512-thr (512 blocks). Per-thread work
// is unchanged (8 phases x 1 b each); table staging fetch halves (64->32MB)
// because half as many blocks stage the same 128KB table. Occupancy
// unchanged: 16 waves/CU (was 2 blocks x 8 waves, now 1 block x 16 waves).
// LDS: 64KB table + 4KB red = 68KB.
// ---------------------------------------------------------------------------
__global__ __launch_bounds__(1024, 4) void k_stats4(
    const int* __restrict__ x, const float* __restrict__ tbl,
    float* __restrict__ psum, float* __restrict__ psq)
{
    __shared__ uint4 tb[TROWS * 4];      // 64KB f16 table: [row][quad of 8 ch]
    __shared__ float red[2][16][32];     // 4KB reduction scratch

    const int m     = blockIdx.x & 63;
    const int chunk = blockIdx.x >> 6;   // 0..3
    const int tid   = threadIdx.x;       // 0..1023
    const int f     = tid & 3;           // channel quad (8 ch) AND t-quad owned
    const int grp   = tid >> 2;          // 0..255 = b within phase
    const int b0    = chunk * 2048;

    // ---- stage + convert table m: f32 128KB -> f16 64KB (4096 uint4) ----
    {
        const float4* __restrict__ src = (const float4*)(tbl + (size_t)m * (TROWS * EM));
#pragma unroll
        for (int i = 0; i < 4; ++i) {
            const int o = tid + i * 1024;            // uint4 index 0..4095
            const float4 a = src[o * 2];
            const float4 c = src[o * 2 + 1];
            uint4 p;
            __half2 h0 = __floats2half2_rn(a.x, a.y);
            __half2 h1 = __floats2half2_rn(a.z, a.w);
            __half2 h2 = __floats2half2_rn(c.x, c.y);
            __half2 h3 = __floats2half2_rn(c.z, c.w);
            p.x = *(unsigned*)&h0; p.y = *(unsigned*)&h1;
            p.z = *(unsigned*)&h2; p.w = *(unsigned*)&h3;
            tb[o] = p;
        }
    }

    // ---- prefetch x for phase 0: ONE int4 per lane (t-quad f of b0+grp) ----
    int4 xr = ((const int4*)(x + (size_t)(b0 + grp) * XROW + m * TT))[f];

    float s[8], s2[8];
#pragma unroll
    for (int k = 0; k < 8; ++k) { s[k] = 0.f; s2[k] = 0.f; }

    __syncthreads();                     // tb ready

    for (int p = 0; p < 8; ++p) {
        int4 nxt = xr;
        if (p < 7)                       // next phase's x; hides behind gather
            nxt = ((const int4*)(x + (size_t)(b0 + (p + 1) * 256 + grp) * XROW + m * TT))[f];

        // all 16 tree indices of this quad's b, via quad broadcast
        const int4 q0 = qbcast<0>(xr);
        const int4 q1 = qbcast<1>(xr);
        const int4 q2 = qbcast<2>(xr);
        const int4 q3 = qbcast<3>(xr);

        __half2 h0 = __half2(__half(0.f), __half(0.f));
        __half2 h1 = h0, h2 = h0, h3 = h0;

#define GATH(Q, RB)                                                          \
        {                                                                    \
            const uint4 a0 = tb[((Q).x + RB      ) * 4 + f];                 \
            const uint4 a1 = tb[((Q).y + RB +  64) * 4 + f];                 \
            const uint4 a2 = tb[((Q).z + RB + 128) * 4 + f];                 \
            const uint4 a3 = tb[((Q).w + RB + 192) * 4 + f];                 \
            h0 = __hadd2(h0, __hadd2(__hadd2(H2(a0.x), H2(a1.x)),            \
                                     __hadd2(H2(a2.x), H2(a3.x))));          \
            h1 = __hadd2(h1, __hadd2(__hadd2(H2(a0.y), H2(a1.y)),            \
                                     __hadd2(H2(a2.y), H2(a3.y))));          \
            h2 = __hadd2(h2, __hadd2(__hadd2(H2(a0.z), H2(a1.z)),            \
                                     __hadd2(H2(a2.z), H2(a3.z))));          \
            h3 = __hadd2(h3, __hadd2(__hadd2(H2(a0.w), H2(a1.w)),            \
                                     __hadd2(H2(a2.w), H2(a3.w))));          \
        }
        GATH(q0, 0) GATH(q1, 256) GATH(q2, 512) GATH(q3, 768)
#undef GATH

        const __half2 hv[4] = {h0, h1, h2, h3};
#pragma unroll
        for (int k = 0; k < 4; ++k) {
            const float lo = __low2float(hv[k]);
            const float hi = __high2float(hv[k]);
            s[2*k]   += lo;  s2[2*k]   = fmaf(lo, lo, s2[2*k]);
            s[2*k+1] += hi;  s2[2*k+1] = fmaf(hi, hi, s2[2*k+1]);
        }
        xr = nxt;
    }

    // ---- reduce over grp: butterfly within wave (grp bits = lane 2..5) ----
#pragma unroll
    for (int off = 4; off <= 32; off <<= 1) {
#pragma unroll
        for (int k = 0; k < 8; ++k) {
            s[k]  += __shfl_xor(s[k],  off);
            s2[k] += __shfl_xor(s2[k], off);
        }
    }
    const int wave = tid >> 6;           // 0..15
    if ((tid & 63) < 4) {
#pragma unroll
        for (int k = 0; k < 8; ++k) {
            red[0][wave][f * 8 + k] = s[k];
            red[1][wave][f * 8 + k] = s2[k];
        }
    }
    __syncthreads();
    if (tid < 32) {
        float a = 0.f, a2 = 0.f;
#pragma unroll
        for (int w = 0; w < 16; ++w) { a += red[0][w][tid]; a2 += red[1][w][tid]; }
        psum[(chunk * NM + m) * EM + tid] = a;   // per-(chunk,m) partials:
        psq [(chunk * NM + m) * EM + tid] = a2;  // no atomics, no memset
    }
}

// ---------------------------------------------------------------------------
// K3'': K2 folded in. Block = (m, chunk) as in R6; each block:
//  (1) finalizes BN from the 4 chunk-partials -> a_s[32], C (32 threads,
//      ~0.5KB of reads) — replaces the K2 dispatch;
//  (2) builds model m's fused strip g2s[row] = dot(tbl[m,row,:], a) in 4KB
//      LDS directly from the f32 table (256B/thread, coalesced; 64MB
//      aggregate but table is L3-resident after K1');
//  (3) gathers: out[b,m] = C + sum_t g2s[t*64 + x[b,m*16+t]], quad-reduced;
//      rowsum via device-scope atomicAdd (out memset-0 by harness).
// bid = m*8+chunk keeps all m-writers of an out-line on one XCD (L2 merge).
// Grid: 512 blocks x 512 threads.
// ---------------------------------------------------------------------------
__global__ __launch_bounds__(512) void k_out4(
    const int* __restrict__ x, const float* __restrict__ tbl,
    const float* __restrict__ gamma, const float* __restrict__ beta,
    const float* __restrict__ bw, const float* __restrict__ bb,
    const float* __restrict__ psum, const float* __restrict__ psq,
    float* __restrict__ out)
{
    __shared__ float g2s[TROWS];         // 4KB: model m's fused table
    __shared__ float a_s[EM + 1];        // BN coeffs + C

    const int m     = blockIdx.x >> 3;
    const int chunk = blockIdx.x & 7;    // = XCD id under round-robin dispatch
    const int tid   = threadIdx.x;
    const int f     = tid & 3;           // t-quad owned (trees f*4..f*4+3)
    const int grp   = tid >> 2;          // 0..127
    const int b0    = chunk * 1024;

    // ---- (1) BN finalize: a[m,e] = istd*gamma*w; C = bb + sum (..)*w ----
    if (tid < 32) {
        const int ch = m * EM + tid;
        float sum = 0.f, sq = 0.f;
#pragma unroll
        for (int c = 0; c < 4; ++c) {
            sum += psum[(c * NM + m) * EM + tid];
            sq  += psq [(c * NM + m) * EM + tid];
        }
        const float inv_n = 1.f / (float)B_TOT;
        const float mean  = sum * inv_n;
        const float var   = sq * inv_n - mean * mean;
        const float gi    = gamma[ch] * rsqrtf(var + 1e-5f);   // istd*gamma
        const float w     = bw[ch];
        a_s[tid] = gi * w;
        float ct = (beta[ch] - mean * gi) * w;
#pragma unroll
        for (int off = 16; off > 0; off >>= 1) ct += __shfl_down(ct, off, 32);
        if (tid == 0) a_s[32] = bb[m] + ct;
    }

    // x loads upfront (32 VGPR); 4 lanes of a quad read one 64B line (b,m)
    int4 xq[8];
#pragma unroll
    for (int p = 0; p < 8; ++p)
        xq[p] = ((const int4*)(x + (size_t)(b0 + p * 128 + grp) * XROW + m * TT))[f];

    __syncthreads();                     // a_s ready

    // ---- (2) g2 strip: thread owns rows 2tid, 2tid+1 (coalesced 256B) ----
    {
        const float4* __restrict__ rp =
            (const float4*)(tbl + (size_t)m * (TROWS * EM)) + tid * 16;
        float acc0 = 0.f, acc1 = 0.f;
#pragma unroll
        for (int i = 0; i < 8; ++i) {
            const float4 v = rp[i];
            acc0 += v.x * a_s[i*4+0] + v.y * a_s[i*4+1]
                  + v.z * a_s[i*4+2] + v.w * a_s[i*4+3];
        }
#pragma unroll
        for (int i = 0; i < 8; ++i) {
            const float4 v = rp[8 + i];
            acc1 += v.x * a_s[i*4+0] + v.y * a_s[i*4+1]
                  + v.z * a_s[i*4+2] + v.w * a_s[i*4+3];
        }
        ((float2*)g2s)[tid] = make_float2(acc0, acc1);   // 2-way bank = free
    }

    const float C = a_s[32];
    const int base = f * 256;            // row = t*64+leaf = f*256 + j*64 + leaf

    __syncthreads();                     // g2s ready

    // ---- (3) gather + quad-reduce + store ----
#pragma unroll
    for (int p = 0; p < 8; ++p) {
        float d = g2s[base       + xq[p].x]
                + g2s[base +  64 + xq[p].y]
                + g2s[base + 128 + xq[p].z]
                + g2s[base + 192 + xq[p].w];
        d += __shfl_xor(d, 1);           // quad-reduce: all 4 lanes get the
        d += __shfl_xor(d, 2);           // sum over 16 trees
        const int b = b0 + p * 128 + grp;
        const float o = d + C;
        if (f == 0) out[B_TOT + (size_t)b * NM + m] = o;   // out tensor (B,M)
        if (f == 1) atomicAdd(&out[b], o);                 // sum_out (B,1)
    }
}

// ---------------------------------------------------------------------------
extern "C" void kernel_launch(void* const* d_in, const int* in_sizes, int n_in,
                              void* d_out, int out_size, void* d_ws, size_t ws_size,
                              hipStream_t stream) {
    const int*   x       = (const int*)d_in[0];
    const float* embed_w = (const float*)d_in[1];
    const float* gamma   = (const float*)d_in[2];
    const float* beta    = (const float*)d_in[3];
    const float* bout_w  = (const float*)d_in[4];
    const float* bout_b  = (const float*)d_in[5];
    float* out = (float*)d_out;

    float* ws   = (float*)d_ws;
    float* psum = ws;                     // 4 chunks x 64 m x 32 e = 8192
    float* psq  = psum + 8192;            // 8192

    k_stats4<<<dim3(256), dim3(1024), 0, stream>>>(x, embed_w, psum, psq);
    k_out4 <<<dim3(512), dim3(512),  0, stream>>>(x, embed_w, gamma, beta,
                                                  bout_w, bout_b, psum, psq, out);
}

// Round 8
// 109.845 us; speedup vs baseline: 1.1141x; 1.1141x over previous
//
#include <hip/hip_runtime.h>
#include <hip/hip_fp16.h>

// Problem constants
constexpr int B_TOT = 8192;      // batch
constexpr int NM    = 64;        // n_models
constexpr int TT    = 16;        // trees per split
constexpr int LF    = 64;        // maxleaf
constexpr int EM    = 32;        // emb dim
constexpr int XROW  = NM * TT;   // 1024 ints per x row
constexpr int TROWS = TT * LF;   // 1024 rows per model table

// Broadcast quad-lane TQ's int4 to all 4 lanes of each quad via DPP
// (VALU pipe — does NOT load the LDS pipe like __shfl/ds_bpermute would).
template<int TQ>
__device__ __forceinline__ int4 qbcast(int4 v) {
    constexpr int c = TQ * 0x55;          // quad_perm [TQ,TQ,TQ,TQ]
    int4 r;
    r.x = __builtin_amdgcn_mov_dpp(v.x, c, 0xf, 0xf, true);
    r.y = __builtin_amdgcn_mov_dpp(v.y, c, 0xf, 0xf, true);
    r.z = __builtin_amdgcn_mov_dpp(v.z, c, 0xf, 0xf, true);
    r.w = __builtin_amdgcn_mov_dpp(v.w, c, 0xf, 0xf, true);
    return r;
}

__device__ __forceinline__ __half2 H2(unsigned u) { return *(const __half2*)&u; }

// ---------------------------------------------------------------------------
// K1: per-channel batch stats from an LDS-resident f16 table.
// PROVEN OPTIMUM (108.6us pipeline, reproduced twice). 8-round ledger:
// every structural deviation regressed — do not touch. 2 blocks/CU matters:
// one block's table-staging latency hides under the other's gather loop
// (R7's 1-block/CU variant exposed it, +9us).
// Block: 512 thr owns model m; 64KB f16 table in LDS; 8 phases x 128 b.
// LDS: 64 + 2 KB -> 2 blocks/CU (16 waves). Grid 512 = 64 m x 8 chunks.
// ---------------------------------------------------------------------------
__global__ __launch_bounds__(512, 4) void k_stats_f16(
    const int* __restrict__ x, const float* __restrict__ tbl,
    float* __restrict__ psum, float* __restrict__ psq)
{
    __shared__ uint4 tb[TROWS * 4];      // 64KB f16 table: [row][quad of 8 ch]
    __shared__ float red[2][8][32];      // 2KB reduction scratch

    const int m     = blockIdx.x & 63;
    const int chunk = blockIdx.x >> 6;   // 0..7
    const int tid   = threadIdx.x;
    const int f     = tid & 3;           // channel quad (8 ch) AND t-quad owned
    const int grp   = tid >> 2;          // 0..127 = b within phase
    const int b0    = chunk * 1024;

    // ---- stage + convert table m: f32 128KB -> f16 64KB (4096 uint4) ----
    {
        const float4* __restrict__ src = (const float4*)(tbl + (size_t)m * (TROWS * EM));
#pragma unroll
        for (int i = 0; i < 8; ++i) {
            const int o = tid + i * 512;             // uint4 index 0..4095
            const float4 a = src[o * 2];
            const float4 c = src[o * 2 + 1];
            uint4 p;
            __half2 h0 = __floats2half2_rn(a.x, a.y);
            __half2 h1 = __floats2half2_rn(a.z, a.w);
            __half2 h2 = __floats2half2_rn(c.x, c.y);
            __half2 h3 = __floats2half2_rn(c.z, c.w);
            p.x = *(unsigned*)&h0; p.y = *(unsigned*)&h1;
            p.z = *(unsigned*)&h2; p.w = *(unsigned*)&h3;
            tb[o] = p;
        }
    }

    // ---- prefetch x for phase 0: ONE int4 per lane (t-quad f of b0+grp) ----
    int4 xr = ((const int4*)(x + (size_t)(b0 + grp) * XROW + m * TT))[f];

    float s[8], s2[8];
#pragma unroll
    for (int k = 0; k < 8; ++k) { s[k] = 0.f; s2[k] = 0.f; }

    __syncthreads();                     // tb ready

    for (int p = 0; p < 8; ++p) {
        int4 nxt = xr;
        if (p < 7)                       // next phase's x; hides behind gather
            nxt = ((const int4*)(x + (size_t)(b0 + (p + 1) * 128 + grp) * XROW + m * TT))[f];

        // all 16 tree indices of this quad's b, via quad broadcast
        const int4 q0 = qbcast<0>(xr);
        const int4 q1 = qbcast<1>(xr);
        const int4 q2 = qbcast<2>(xr);
        const int4 q3 = qbcast<3>(xr);

        __half2 h0 = __half2(__half(0.f), __half(0.f));
        __half2 h1 = h0, h2 = h0, h3 = h0;

#define GATH(Q, RB)                                                          \
        {                                                                    \
            const uint4 a0 = tb[((Q).x + RB      ) * 4 + f];                 \
            const uint4 a1 = tb[((Q).y + RB +  64) * 4 + f];                 \
            const uint4 a2 = tb[((Q).z + RB + 128) * 4 + f];                 \
            const uint4 a3 = tb[((Q).w + RB + 192) * 4 + f];                 \
            h0 = __hadd2(h0, __hadd2(__hadd2(H2(a0.x), H2(a1.x)),            \
                                     __hadd2(H2(a2.x), H2(a3.x))));          \
            h1 = __hadd2(h1, __hadd2(__hadd2(H2(a0.y), H2(a1.y)),            \
                                     __hadd2(H2(a2.y), H2(a3.y))));          \
            h2 = __hadd2(h2, __hadd2(__hadd2(H2(a0.z), H2(a1.z)),            \
                                     __hadd2(H2(a2.z), H2(a3.z))));          \
            h3 = __hadd2(h3, __hadd2(__hadd2(H2(a0.w), H2(a1.w)),            \
                                     __hadd2(H2(a2.w), H2(a3.w))));          \
        }
        GATH(q0, 0) GATH(q1, 256) GATH(q2, 512) GATH(q3, 768)
#undef GATH

        const __half2 hv[4] = {h0, h1, h2, h3};
#pragma unroll
        for (int k = 0; k < 4; ++k) {
            const float lo = __low2float(hv[k]);
            const float hi = __high2float(hv[k]);
            s[2*k]   += lo;  s2[2*k]   = fmaf(lo, lo, s2[2*k]);
            s[2*k+1] += hi;  s2[2*k+1] = fmaf(hi, hi, s2[2*k+1]);
        }
        xr = nxt;
    }

    // ---- reduce over grp: butterfly within wave (grp bits = lane 2..5) ----
#pragma unroll
    for (int off = 4; off <= 32; off <<= 1) {
#pragma unroll
        for (int k = 0; k < 8; ++k) {
            s[k]  += __shfl_xor(s[k],  off);
            s2[k] += __shfl_xor(s2[k], off);
        }
    }
    const int wave = tid >> 6;
    if ((tid & 63) < 4) {
#pragma unroll
        for (int k = 0; k < 8; ++k) {
            red[0][wave][f * 8 + k] = s[k];
            red[1][wave][f * 8 + k] = s2[k];
        }
    }
    __syncthreads();
    if (tid < 32) {
        float a = 0.f, a2 = 0.f;
#pragma unroll
        for (int w = 0; w < 8; ++w) { a += red[0][w][tid]; a2 += red[1][w][tid]; }
        psum[(chunk * NM + m) * EM + tid] = a;   // per-(chunk,m) partials:
        psq [(chunk * NM + m) * EM + tid] = a2;  // no atomics, no memset
    }
}

// ---------------------------------------------------------------------------
// K2: sum the 8 chunk-partials, fold BN + projection:
//   a[m,e]=istd*gamma*w; C[m]=bout_b[m]+sum_e (beta-mean*istd*gamma)*w
//   g2[row*64+m] = dot(tbl[m,row,:], a[m,:])
// Grid: 256 blocks = 64 m x 4 row-quarters, 256 threads.
// ---------------------------------------------------------------------------
__global__ __launch_bounds__(256) void k_prep(
    const float* __restrict__ tbl,
    const float* __restrict__ gamma, const float* __restrict__ beta,
    const float* __restrict__ bw, const float* __restrict__ bb,
    const float* __restrict__ psum, const float* __restrict__ psq,
    float* __restrict__ Cm, float* __restrict__ g2)
{
    const int m    = blockIdx.x >> 2;
    const int part = blockIdx.x & 3;
    __shared__ float a_s[EM];
    if (threadIdx.x < EM) {
        const int e  = threadIdx.x;
        const int ch = m * EM + e;
        float sum = 0.f, sq = 0.f;
#pragma unroll
        for (int c = 0; c < 8; ++c) {
            sum += psum[(c * NM + m) * EM + e];
            sq  += psq [(c * NM + m) * EM + e];
        }
        const float inv_n = 1.f / (float)B_TOT;
        const float mean = sum * inv_n;
        const float var  = sq * inv_n - mean * mean;
        const float istd = rsqrtf(var + 1e-5f);
        const float g = gamma[ch];
        const float w = bw[ch];
        a_s[e] = istd * g * w;
        float ct = (beta[ch] - mean * istd * g) * w;
#pragma unroll
        for (int off = 16; off > 0; off >>= 1) ct += __shfl_down(ct, off, 32);
        if (e == 0 && part == 0) Cm[m] = bb[m] + ct;
    }
    __syncthreads();

    const float* __restrict__ tblm = tbl + (size_t)m * (TROWS * EM);
    const int row = part * 256 + threadIdx.x;
    const float4* rp = (const float4*)(tblm + row * EM);
    float acc = 0.f;
#pragma unroll
    for (int i = 0; i < 8; ++i) {
        const float4 v = rp[i];
        acc += v.x * a_s[i*4+0] + v.y * a_s[i*4+1]
             + v.z * a_s[i*4+2] + v.w * a_s[i*4+3];
    }
    g2[row * NM + m] = acc;
}

// ---------------------------------------------------------------------------
// K3: out[b,m] = C[m] + sum_t g2[(t*64 + x[b,m*16+t])*64 + m]; plus row sum.
// 64KB slab (quarter of g2) x 4 phases -> 2 blocks/CU co-resident.
// Grid: 512 blocks x 1024 threads (16 b per block). Slab gather bank =
// m&31 -> 2 lanes/bank = free.
// ---------------------------------------------------------------------------
__global__ __launch_bounds__(1024, 8) void k_out(
    const int* __restrict__ x, const float* __restrict__ g2,
    const float* __restrict__ Cm, float* __restrict__ out)
{
    __shared__ float slab[4 * LF * NM];      // 64KB
    const int tid  = threadIdx.x;
    const int wid  = tid >> 6;               // 0..15
    const int lane = tid & 63;               // = m
    const int b    = blockIdx.x * 16 + wid;

    const int4* xp = (const int4*)(x + (size_t)b * XROW + lane * TT);
    const int4 q0 = xp[0], q1 = xp[1], q2 = xp[2], q3 = xp[3];
    const int idxs[16] = {q0.x,q0.y,q0.z,q0.w, q1.x,q1.y,q1.z,q1.w,
                          q2.x,q2.y,q2.z,q2.w, q3.x,q3.y,q3.z,q3.w};

    float acc = 0.f;
#pragma unroll
    for (int ph = 0; ph < 4; ++ph) {
        if (ph) __syncthreads();             // done reading previous slab
        const float4* src = (const float4*)(g2 + (size_t)ph * (4 * LF * NM));
        float4* dst = (float4*)slab;
#pragma unroll
        for (int j = 0; j < 4; ++j) dst[tid + j * 1024] = src[tid + j * 1024];
        __syncthreads();
#pragma unroll
        for (int tt = 0; tt < 4; ++tt)
            acc += slab[tt * (LF * NM) + idxs[ph * 4 + tt] * NM + lane];
    }

    const float o = acc + Cm[lane];
    float s = o;
#pragma unroll
    for (int off = 32; off > 0; off >>= 1) s += __shfl_down(s, off);
    out[B_TOT + (size_t)b * NM + lane] = o;  // out tensor (B, M)
    if (lane == 0) out[b] = s;               // sum_out (B, 1)
}

// ---------------------------------------------------------------------------
extern "C" void kernel_launch(void* const* d_in, const int* in_sizes, int n_in,
                              void* d_out, int out_size, void* d_ws, size_t ws_size,
                              hipStream_t stream) {
    const int*   x       = (const int*)d_in[0];
    const float* embed_w = (const float*)d_in[1];
    const float* gamma   = (const float*)d_in[2];
    const float* beta    = (const float*)d_in[3];
    const float* bout_w  = (const float*)d_in[4];
    const float* bout_b  = (const float*)d_in[5];
    float* out = (float*)d_out;

    float* ws   = (float*)d_ws;
    float* Cm   = ws;                 // 64
    float* g2   = ws + 64;            // 65536
    float* psum = ws + 64 + 65536;    // 8 chunks x 64 m x 32 e = 16384
    float* psq  = psum + 16384;       // 16384   (total ~392KB)

    k_stats_f16<<<dim3(512), dim3(512), 0, stream>>>(x, embed_w, psum, psq);
    k_prep<<<dim3(256), dim3(256),  0, stream>>>(embed_w, gamma, beta, bout_w,
                                                 bout_b, psum, psq, Cm, g2);
    k_out <<<dim3(512), dim3(1024), 0, stream>>>(x, g2, Cm, out);
}